// Round 1
// baseline (649.152 us; speedup 1.0000x reference)
//
#include <hip/hip_runtime.h>
#include <stdint.h>

typedef uint16_t u16;
typedef __bf16 bf16x8 __attribute__((ext_vector_type(8)));
typedef float f32x4 __attribute__((ext_vector_type(4)));

#define DEV static __device__ __forceinline__

DEV float bfbits_lo(uint32_t w) { union { uint32_t i; float f; } v; v.i = w << 16; return v.f; }
DEV float bfbits_hi(uint32_t w) { union { uint32_t i; float f; } v; v.i = w & 0xffff0000u; return v.f; }
DEV u16 f2bf(float f) {
    union { float f; uint32_t i; } v; v.f = f;
    uint32_t x = v.i;
    uint32_t r = (x + 0x7fffu + ((x >> 16) & 1u)) >> 16;  // RNE
    return (u16)r;
}

// ---------------------------------------------------------------- KNN ----
// wave per query (b,n): 16 dists/lane in regs, 20x wave-argmin extraction.
__global__ __launch_bounds__(256) void knn_kernel(const float* __restrict__ verts,
                                                  int* __restrict__ nbr) {
    int tid = threadIdx.x;
    int wv = blockIdx.x * 4 + (tid >> 6);   // global (b*1024+n)
    int l = tid & 63;
    int b = wv >> 10, n = wv & 1023;
    const float* vb = verts + (size_t)b * 1024 * 3;
    float qx = vb[n * 3 + 0], qy = vb[n * 3 + 1], qz = vb[n * 3 + 2];
    float q2 = qx * qx + qy * qy + qz * qz;
    float d[16];
#pragma unroll
    for (int t = 0; t < 16; t++) {
        int p = l + 64 * t;
        float px = vb[p * 3 + 0], py = vb[p * 3 + 1], pz = vb[p * 3 + 2];
        float p2 = px * px + py * py + pz * pz;
        float dot = qx * px + qy * py + qz * pz;
        d[t] = q2 + p2 - 2.f * dot;   // same formula as reference
    }
    int* outp = nbr + (size_t)wv * 20;
    for (int it = 0; it < 20; it++) {
        float dm = d[0]; int im = 0;
#pragma unroll
        for (int t = 1; t < 16; t++) { if (d[t] < dm) { dm = d[t]; im = t; } }
        int g = im * 64 + l;
#pragma unroll
        for (int off = 32; off >= 1; off >>= 1) {
            float od = __shfl_xor(dm, off);
            int og = __shfl_xor(g, off);
            if (od < dm || (od == dm && og < g)) { dm = od; g = og; }
        }
        int wl = g & 63, wt = g >> 6;
        if (l == wl) {
#pragma unroll
            for (int t = 0; t < 16; t++) if (t == wt) d[t] = 3.4e38f;
        }
        if (l == 0) outp[it] = g;
    }
}

// -------------------------------------------------------- fp32 -> bf16 ----
__global__ __launch_bounds__(256) void convertF(const float* __restrict__ in,
                                                u16* __restrict__ out) {
    int i = blockIdx.x * 256 + threadIdx.x;   // 8 elems each
    const float4* p = (const float4*)in + (size_t)i * 2;
    float4 a = p[0], c = p[1];
    uint32_t w0 = f2bf(a.x) | ((uint32_t)f2bf(a.y) << 16);
    uint32_t w1 = f2bf(a.z) | ((uint32_t)f2bf(a.w) << 16);
    uint32_t w2 = f2bf(c.x) | ((uint32_t)f2bf(c.y) << 16);
    uint32_t w3 = f2bf(c.z) | ((uint32_t)f2bf(c.w) << 16);
    ((uint4*)out)[i] = make_uint4(w0, w1, w2, w3);
}

// --------------------------------------- transpose + convert W[K,N]->bf16 WT[N,K]
__global__ __launch_bounds__(256) void transposeW(const float* __restrict__ in,
                                                  u16* __restrict__ out,
                                                  int K, int N) {
    __shared__ float tile[32][33];
    int tx = threadIdx.x & 31, ty = threadIdx.x >> 5;  // 32 x 8
    int x0 = blockIdx.x * 32, y0 = blockIdx.y * 32;
#pragma unroll
    for (int r = 0; r < 4; r++) {
        int y = y0 + ty + r * 8;
        tile[ty + r * 8][tx] = in[(size_t)y * N + x0 + tx];
    }
    __syncthreads();
#pragma unroll
    for (int r = 0; r < 4; r++) {
        int nrow = x0 + ty + r * 8;
        out[(size_t)nrow * K + y0 + tx] = f2bf(tile[tx][ty + r * 8]);
    }
}

__global__ void concat_bias(const float* __restrict__ bq, const float* __restrict__ bk,
                            const float* __restrict__ bv, float* __restrict__ outb) {
    int i = blockIdx.x * 256 + threadIdx.x;
    if (i < 1024) outb[i] = bq[i];
    else if (i < 2048) outb[i] = bk[i - 1024];
    else if (i < 3072) outb[i] = bv[i - 2048];
}

// ---------------------------------------------------------------- GEMM ----
// C[M,N] = A[M,K] * BT[N,K]^T, bf16 inputs, fp32 accum (MFMA 16x16x32).
// 128x128 tile, BK=32, global_load_lds(16B) staging, quad-plane LDS layout.
// EPI: 0 = bias -> bf16, 1 = bias+relu -> bf16, 2 = bias+residual -> fp32
template <int EPI>
__global__ __launch_bounds__(256) void gemm_bt(const u16* __restrict__ A,
                                               const u16* __restrict__ BT,
                                               const float* __restrict__ bias,
                                               const float* __restrict__ res,
                                               u16* __restrict__ Cb,
                                               float* __restrict__ Cf,
                                               int M, int N, int K) {
    __shared__ __align__(16) u16 As[4 * 128 * 8];
    __shared__ __align__(16) u16 Bs[4 * 128 * 8];
    int tid = threadIdx.x;
    int m0 = blockIdx.y * 128, n0 = blockIdx.x * 128;
    int w = tid >> 6, l = tid & 63;
    int wr = w >> 1, wc = w & 1, quad = l >> 4, ln = l & 15;

    f32x4 acc[4][4];
#pragma unroll
    for (int i = 0; i < 4; i++)
#pragma unroll
        for (int j = 0; j < 4; j++) acc[i][j] = (f32x4){0.f, 0.f, 0.f, 0.f};

    for (int kt = 0; kt < K; kt += 32) {
        __syncthreads();
        {
            int idx = tid, q = idx >> 7, r = idx & 127;
            __builtin_amdgcn_global_load_lds(
                (const __attribute__((address_space(1))) void*)(A + (size_t)(m0 + r) * K + kt + q * 8),
                (__attribute__((address_space(3))) void*)((char*)As + idx * 16), 16, 0, 0);
            idx = tid + 256; q = idx >> 7; r = idx & 127;
            __builtin_amdgcn_global_load_lds(
                (const __attribute__((address_space(1))) void*)(A + (size_t)(m0 + r) * K + kt + q * 8),
                (__attribute__((address_space(3))) void*)((char*)As + idx * 16), 16, 0, 0);
            idx = tid; q = idx >> 7; r = idx & 127;
            __builtin_amdgcn_global_load_lds(
                (const __attribute__((address_space(1))) void*)(BT + (size_t)(n0 + r) * K + kt + q * 8),
                (__attribute__((address_space(3))) void*)((char*)Bs + idx * 16), 16, 0, 0);
            idx = tid + 256; q = idx >> 7; r = idx & 127;
            __builtin_amdgcn_global_load_lds(
                (const __attribute__((address_space(1))) void*)(BT + (size_t)(n0 + r) * K + kt + q * 8),
                (__attribute__((address_space(3))) void*)((char*)Bs + idx * 16), 16, 0, 0);
        }
        __syncthreads();
        const bf16x8* Av = (const bf16x8*)As;
        const bf16x8* Bv = (const bf16x8*)Bs;
        bf16x8 af[4], bfr[4];
#pragma unroll
        for (int i = 0; i < 4; i++) af[i] = Av[quad * 128 + wr * 64 + i * 16 + ln];
#pragma unroll
        for (int j = 0; j < 4; j++) bfr[j] = Bv[quad * 128 + wc * 64 + j * 16 + ln];
#pragma unroll
        for (int i = 0; i < 4; i++)
#pragma unroll
            for (int j = 0; j < 4; j++)
                acc[i][j] = __builtin_amdgcn_mfma_f32_16x16x32_bf16(af[i], bfr[j], acc[i][j], 0, 0, 0);
    }
    // epilogue: C row = m0+wr*64+i*16+quad*4+r, col = n0+wc*64+j*16+ln
#pragma unroll
    for (int i = 0; i < 4; i++) {
        int row_base = m0 + wr * 64 + i * 16 + quad * 4;
#pragma unroll
        for (int j = 0; j < 4; j++) {
            int col = n0 + wc * 64 + j * 16 + ln;
            float bb = bias[col];
#pragma unroll
            for (int r = 0; r < 4; r++) {
                int row = row_base + r;
                size_t o = (size_t)row * N + col;
                float v = acc[i][j][r] + bb;
                if (EPI == 0) Cb[o] = f2bf(v);
                else if (EPI == 1) Cb[o] = f2bf(v > 0.f ? v : 0.f);
                else Cf[o] = v + res[o];
            }
        }
    }
}

// ----------------------------------------------------- sparse attention ----
// wave per (b,n); 16 lanes per head; 20 gathered neighbors; softmax in regs.
__global__ __launch_bounds__(256) void attn_kernel(const u16* __restrict__ QKV,
                                                   const int* __restrict__ nbr,
                                                   u16* __restrict__ outA) {
    int tid = threadIdx.x;
    int wv = blockIdx.x * 4 + (tid >> 6);  // b*1024+n
    int l = tid & 63;
    int h = l >> 4, sx = l & 15;
    int bbase = (wv >> 10) << 10;

    int nv = 0;
    if (l < 20) nv = nbr[(size_t)wv * 20 + l];

    const uint32_t* qp = (const uint32_t*)(QKV + (size_t)wv * 3072 + h * 256 + sx * 16);
    uint32_t qw[8];
    *(uint4*)(qw) = *(const uint4*)qp;
    *(uint4*)(qw + 4) = *(const uint4*)(qp + 4);
    float qf[16];
#pragma unroll
    for (int i = 0; i < 8; i++) { qf[2 * i] = bfbits_lo(qw[i]); qf[2 * i + 1] = bfbits_hi(qw[i]); }

    float wj[20];
#pragma unroll
    for (int j = 0; j < 20; j++) {
        int m = __shfl(nv, j);
        const uint32_t* kp = (const uint32_t*)(QKV + (size_t)(bbase + m) * 3072 + 1024 + h * 256 + sx * 16);
        uint32_t kw[8];
        *(uint4*)(kw) = *(const uint4*)kp;
        *(uint4*)(kw + 4) = *(const uint4*)(kp + 4);
        float acc = 0.f;
#pragma unroll
        for (int i = 0; i < 8; i++) {
            acc += qf[2 * i] * bfbits_lo(kw[i]);
            acc += qf[2 * i + 1] * bfbits_hi(kw[i]);
        }
#pragma unroll
        for (int off = 1; off < 16; off <<= 1) acc += __shfl_xor(acc, off);
        wj[j] = acc * 0.0625f;   // / sqrt(256)
    }
    float mx = wj[0];
#pragma unroll
    for (int j = 1; j < 20; j++) mx = fmaxf(mx, wj[j]);
    float ssum = 0.f;
#pragma unroll
    for (int j = 0; j < 20; j++) { wj[j] = __expf(wj[j] - mx); ssum += wj[j]; }
    float inv = 1.f / ssum;

    float o[16];
#pragma unroll
    for (int i = 0; i < 16; i++) o[i] = 0.f;
#pragma unroll
    for (int j = 0; j < 20; j++) {
        int m = __shfl(nv, j);
        const uint32_t* vp = (const uint32_t*)(QKV + (size_t)(bbase + m) * 3072 + 2048 + h * 256 + sx * 16);
        uint32_t vw[8];
        *(uint4*)(vw) = *(const uint4*)vp;
        *(uint4*)(vw + 4) = *(const uint4*)(vp + 4);
        float ww = wj[j] * inv;
#pragma unroll
        for (int i = 0; i < 8; i++) {
            o[2 * i] += ww * bfbits_lo(vw[i]);
            o[2 * i + 1] += ww * bfbits_hi(vw[i]);
        }
    }
    uint32_t ow[8];
#pragma unroll
    for (int i = 0; i < 8; i++) ow[i] = f2bf(o[2 * i]) | ((uint32_t)f2bf(o[2 * i + 1]) << 16);
    u16* op = outA + (size_t)wv * 1024 + h * 256 + sx * 16;
    *(uint4*)op = *(uint4*)ow;
    *((uint4*)op + 1) = *(uint4*)(ow + 4);
}

// ------------------------------------------------------------ LayerNorm ----
// wave per row of 512; WB: also write bf16 copy.
template <int WB>
__global__ __launch_bounds__(256) void ln_kernel(const float* __restrict__ X,
                                                 const float* __restrict__ g,
                                                 const float* __restrict__ bparm,
                                                 float* __restrict__ Yf,
                                                 u16* __restrict__ Yb) {
    int tid = threadIdx.x;
    int row = blockIdx.x * 4 + (tid >> 6);
    int l = tid & 63;
    const float4* xr = (const float4*)(X + (size_t)row * 512) + l * 2;
    float4 a = xr[0], c = xr[1];
    float xs[8] = {a.x, a.y, a.z, a.w, c.x, c.y, c.z, c.w};
    float s = 0.f;
#pragma unroll
    for (int i = 0; i < 8; i++) s += xs[i];
#pragma unroll
    for (int off = 32; off >= 1; off >>= 1) s += __shfl_xor(s, off);
    float mu = s * (1.f / 512.f);
    float q = 0.f;
#pragma unroll
    for (int i = 0; i < 8; i++) { float dd = xs[i] - mu; q += dd * dd; }
#pragma unroll
    for (int off = 32; off >= 1; off >>= 1) q += __shfl_xor(q, off);
    float var = q * (1.f / 512.f);
    float rs = rsqrtf(var + 1e-5f);
    const float4* gp = (const float4*)g + l * 2;
    const float4* bp = (const float4*)bparm + l * 2;
    float4 g0 = gp[0], g1 = gp[1], b0 = bp[0], b1 = bp[1];
    float gg[8] = {g0.x, g0.y, g0.z, g0.w, g1.x, g1.y, g1.z, g1.w};
    float bbv[8] = {b0.x, b0.y, b0.z, b0.w, b1.x, b1.y, b1.z, b1.w};
    float y[8];
#pragma unroll
    for (int i = 0; i < 8; i++) y[i] = (xs[i] - mu) * rs * gg[i] + bbv[i];
    float4* yo = (float4*)(Yf + (size_t)row * 512) + l * 2;
    yo[0] = make_float4(y[0], y[1], y[2], y[3]);
    yo[1] = make_float4(y[4], y[5], y[6], y[7]);
    if (WB) {
        uint32_t w0 = f2bf(y[0]) | ((uint32_t)f2bf(y[1]) << 16);
        uint32_t w1 = f2bf(y[2]) | ((uint32_t)f2bf(y[3]) << 16);
        uint32_t w2 = f2bf(y[4]) | ((uint32_t)f2bf(y[5]) << 16);
        uint32_t w3 = f2bf(y[6]) | ((uint32_t)f2bf(y[7]) << 16);
        *(uint4*)(Yb + (size_t)row * 512 + l * 8) = make_uint4(w0, w1, w2, w3);
    }
}

// ------------------------------------------------------------ launcher ----
extern "C" void kernel_launch(void* const* d_in, const int* in_sizes, int n_in,
                              void* d_out, int out_size, void* d_ws, size_t ws_size,
                              hipStream_t stream) {
    const float* verts = (const float*)d_in[0];
    const float* F = (const float*)d_in[1];
    const float* Wq = (const float*)d_in[2];
    const float* bq = (const float*)d_in[3];
    const float* Wk = (const float*)d_in[4];
    const float* bk = (const float*)d_in[5];
    const float* Wv = (const float*)d_in[6];
    const float* bv = (const float*)d_in[7];
    const float* Wo = (const float*)d_in[8];
    const float* bo = (const float*)d_in[9];
    const float* ln1g = (const float*)d_in[10];
    const float* ln1b = (const float*)d_in[11];
    const float* W1 = (const float*)d_in[12];
    const float* b1 = (const float*)d_in[13];
    const float* W2 = (const float*)d_in[14];
    const float* b2 = (const float*)d_in[15];
    const float* ln2g = (const float*)d_in[16];
    const float* ln2b = (const float*)d_in[17];
    float* out = (float*)d_out;

    char* ws = (char*)d_ws;
    // arena layout (lifetime-overlapped):
    u16* QKV = (u16*)(ws);                        // 100,663,296 B ; later reused as H
    u16* ATT = (u16*)(ws + 100663296);            //  33,554,432 B ; later reused as xb
    float* X32 = (float*)(ws + 134217728);        //  33,554,432 B ; early reused as Fb
    u16* Fb = (u16*)(ws + 134217728);
    u16* xb = ATT;
    u16* Hb = QKV;
    char* wsw = ws + 167772160;
    u16* WqkvT = (u16*)(wsw);                     // 3,145,728
    u16* WoT = (u16*)(wsw + 3145728);             // 1,048,576
    u16* W1T = (u16*)(wsw + 4194304);             // 2,097,152
    u16* W2T = (u16*)(wsw + 6291456);             // 2,097,152
    float* bqkv = (float*)(wsw + 8388608);        // 12,288
    int* nbr = (int*)(wsw + 8402944);             // 1,310,720  (arena total ~177.5 MB)

    knn_kernel<<<4096, 256, 0, stream>>>(verts, nbr);
    convertF<<<4096, 256, 0, stream>>>(F, Fb);                       // 16384*512
    transposeW<<<dim3(32, 16), 256, 0, stream>>>(Wq, WqkvT, 512, 1024);
    transposeW<<<dim3(32, 16), 256, 0, stream>>>(Wk, WqkvT + 1024 * 512, 512, 1024);
    transposeW<<<dim3(32, 16), 256, 0, stream>>>(Wv, WqkvT + 2048 * 512, 512, 1024);
    transposeW<<<dim3(16, 32), 256, 0, stream>>>(Wo, WoT, 1024, 512);
    transposeW<<<dim3(64, 16), 256, 0, stream>>>(W1, W1T, 512, 2048);
    transposeW<<<dim3(16, 64), 256, 0, stream>>>(W2, W2T, 2048, 512);
    concat_bias<<<12, 256, 0, stream>>>(bq, bk, bv, bqkv);

    // G1: QKV = Fb @ Wqkv + bias -> bf16 [16384, 3072]
    gemm_bt<0><<<dim3(24, 128), 256, 0, stream>>>(Fb, WqkvT, bqkv, nullptr, QKV, nullptr, 16384, 3072, 512);
    // sparse attention -> ATT bf16 [16384, 1024]
    attn_kernel<<<4096, 256, 0, stream>>>(QKV, nbr, ATT);
    // G2: pre1 = ATT @ Wo + bo + F -> d_out fp32 [16384, 512]
    gemm_bt<2><<<dim3(4, 128), 256, 0, stream>>>(ATT, WoT, bo, F, nullptr, out, 16384, 512, 1024);
    // LN1: d_out -> X32 fp32 + xb bf16
    ln_kernel<1><<<4096, 256, 0, stream>>>(out, ln1g, ln1b, X32, xb);
    // G3: H = relu(xb @ W1 + b1) -> bf16 [16384, 2048]
    gemm_bt<1><<<dim3(16, 128), 256, 0, stream>>>(xb, W1T, b1, nullptr, Hb, nullptr, 16384, 2048, 512);
    // G4: pre2 = H @ W2 + b2 + X32 -> d_out fp32
    gemm_bt<2><<<dim3(4, 128), 256, 0, stream>>>(Hb, W2T, b2, X32, nullptr, out, 16384, 512, 2048);
    // LN2 in-place on d_out
    ln_kernel<0><<<4096, 256, 0, stream>>>(out, ln2g, ln2b, out, nullptr);
}

// Round 2
// 643.090 us; speedup vs baseline: 1.0094x; 1.0094x over previous
//
#include <hip/hip_runtime.h>
#include <stdint.h>

typedef uint16_t u16;
typedef __bf16 bf16x8 __attribute__((ext_vector_type(8)));
typedef float f32x4 __attribute__((ext_vector_type(4)));

#define DEV static __device__ __forceinline__

DEV float bfbits_lo(uint32_t w) { union { uint32_t i; float f; } v; v.i = w << 16; return v.f; }
DEV float bfbits_hi(uint32_t w) { union { uint32_t i; float f; } v; v.i = w & 0xffff0000u; return v.f; }
DEV u16 f2bf(float f) {
    union { float f; uint32_t i; } v; v.f = f;
    uint32_t x = v.i;
    uint32_t r = (x + 0x7fffu + ((x >> 16) & 1u)) >> 16;  // RNE
    return (u16)r;
}

// ---------------------------------------------------------------- KNN ----
__global__ __launch_bounds__(256) void knn_kernel(const float* __restrict__ verts,
                                                  int* __restrict__ nbr) {
    int tid = threadIdx.x;
    int wv = blockIdx.x * 4 + (tid >> 6);   // global (b*1024+n)
    int l = tid & 63;
    int b = wv >> 10, n = wv & 1023;
    const float* vb = verts + (size_t)b * 1024 * 3;
    float qx = vb[n * 3 + 0], qy = vb[n * 3 + 1], qz = vb[n * 3 + 2];
    float q2 = qx * qx + qy * qy + qz * qz;
    float d[16];
#pragma unroll
    for (int t = 0; t < 16; t++) {
        int p = l + 64 * t;
        float px = vb[p * 3 + 0], py = vb[p * 3 + 1], pz = vb[p * 3 + 2];
        float p2 = px * px + py * py + pz * pz;
        float dot = qx * px + qy * py + qz * pz;
        d[t] = q2 + p2 - 2.f * dot;
    }
    int* outp = nbr + (size_t)wv * 20;
    for (int it = 0; it < 20; it++) {
        float dm = d[0]; int im = 0;
#pragma unroll
        for (int t = 1; t < 16; t++) { if (d[t] < dm) { dm = d[t]; im = t; } }
        int g = im * 64 + l;
#pragma unroll
        for (int off = 32; off >= 1; off >>= 1) {
            float od = __shfl_xor(dm, off);
            int og = __shfl_xor(g, off);
            if (od < dm || (od == dm && og < g)) { dm = od; g = og; }
        }
        int wl = g & 63, wt = g >> 6;
        if (l == wl) {
#pragma unroll
            for (int t = 0; t < 16; t++) if (t == wt) d[t] = 3.4e38f;
        }
        if (l == 0) outp[it] = g;
    }
}

// -------------------------------------------------------- fp32 -> bf16 ----
__global__ __launch_bounds__(256) void convertF(const float* __restrict__ in,
                                                u16* __restrict__ out) {
    int i = blockIdx.x * 256 + threadIdx.x;   // 8 elems each
    const float4* p = (const float4*)in + (size_t)i * 2;
    float4 a = p[0], c = p[1];
    uint32_t w0 = f2bf(a.x) | ((uint32_t)f2bf(a.y) << 16);
    uint32_t w1 = f2bf(a.z) | ((uint32_t)f2bf(a.w) << 16);
    uint32_t w2 = f2bf(c.x) | ((uint32_t)f2bf(c.y) << 16);
    uint32_t w3 = f2bf(c.z) | ((uint32_t)f2bf(c.w) << 16);
    ((uint4*)out)[i] = make_uint4(w0, w1, w2, w3);
}

// --------------------------------------- transpose + convert W[K,N]->bf16 WT[N,K]
__global__ __launch_bounds__(256) void transposeW(const float* __restrict__ in,
                                                  u16* __restrict__ out,
                                                  int K, int N) {
    __shared__ float tile[32][33];
    int tx = threadIdx.x & 31, ty = threadIdx.x >> 5;  // 32 x 8
    int x0 = blockIdx.x * 32, y0 = blockIdx.y * 32;
#pragma unroll
    for (int r = 0; r < 4; r++) {
        int y = y0 + ty + r * 8;
        tile[ty + r * 8][tx] = in[(size_t)y * N + x0 + tx];
    }
    __syncthreads();
#pragma unroll
    for (int r = 0; r < 4; r++) {
        int nrow = x0 + ty + r * 8;
        out[(size_t)nrow * K + y0 + tx] = f2bf(tile[tx][ty + r * 8]);
    }
}

__global__ void concat_bias(const float* __restrict__ bq, const float* __restrict__ bk,
                            const float* __restrict__ bv, float* __restrict__ outb) {
    int i = blockIdx.x * 256 + threadIdx.x;
    if (i < 1024) outb[i] = bq[i];
    else if (i < 2048) outb[i] = bk[i - 1024];
    else if (i < 3072) outb[i] = bv[i - 2048];
}

// ---------------------------------------------------------------- GEMM ----
// C[M,N] = A[M,K] * BT[N,K]^T, bf16 in, fp32 accum, MFMA 16x16x32, BK=64.
// Column-major block remap: XCD k owns rows y=k (mod 8) -> A slab L2-resident.
// EPI: 0 bias->bf16 | 1 bias+relu->bf16 | 2 bias+res->fp32 | 3 partial->fp32
template <int EPI>
__global__ __launch_bounds__(256) void gemm_bt(const u16* __restrict__ A,
                                               const u16* __restrict__ BT,
                                               const float* __restrict__ bias,
                                               const float* __restrict__ res,
                                               u16* __restrict__ Cb,
                                               float* __restrict__ Cf,
                                               int M, int N, int Klen, int lda, int ldb) {
    __shared__ __align__(16) u16 As[8 * 128 * 8];   // [kkq 0..7][row 0..127][8 bf16]
    __shared__ __align__(16) u16 Bs[8 * 128 * 8];
    int tid = threadIdx.x;
    // column-major remap for XCD L2 locality on the A slab
    int id = blockIdx.y * gridDim.x + blockIdx.x;
    int by = id % gridDim.y, bx = id / gridDim.y;
    int m0 = by * 128, n0 = bx * 128;
    int w = tid >> 6, l = tid & 63;
    int wr = w >> 1, wc = w & 1, quad = l >> 4, ln = l & 15;

    f32x4 acc[4][4];
#pragma unroll
    for (int i = 0; i < 4; i++)
#pragma unroll
        for (int j = 0; j < 4; j++) acc[i][j] = (f32x4){0.f, 0.f, 0.f, 0.f};

    for (int kt = 0; kt < Klen; kt += 64) {
        __syncthreads();
#pragma unroll
        for (int c = 0; c < 4; c++) {
            int idx = c * 256 + tid, kkq = idx >> 7, r = idx & 127;
            __builtin_amdgcn_global_load_lds(
                (const __attribute__((address_space(1))) void*)(A + (size_t)(m0 + r) * lda + kt + kkq * 8),
                (__attribute__((address_space(3))) void*)((char*)As + idx * 16), 16, 0, 0);
        }
#pragma unroll
        for (int c = 0; c < 4; c++) {
            int idx = c * 256 + tid, kkq = idx >> 7, r = idx & 127;
            __builtin_amdgcn_global_load_lds(
                (const __attribute__((address_space(1))) void*)(BT + (size_t)(n0 + r) * ldb + kt + kkq * 8),
                (__attribute__((address_space(3))) void*)((char*)Bs + idx * 16), 16, 0, 0);
        }
        __syncthreads();
        const bf16x8* Av = (const bf16x8*)As;
        const bf16x8* Bv = (const bf16x8*)Bs;
#pragma unroll
        for (int kk = 0; kk < 2; kk++) {
            bf16x8 af[4], bfr[4];
#pragma unroll
            for (int i = 0; i < 4; i++) af[i] = Av[(kk * 4 + quad) * 128 + wr * 64 + i * 16 + ln];
#pragma unroll
            for (int j = 0; j < 4; j++) bfr[j] = Bv[(kk * 4 + quad) * 128 + wc * 64 + j * 16 + ln];
#pragma unroll
            for (int i = 0; i < 4; i++)
#pragma unroll
                for (int j = 0; j < 4; j++)
                    acc[i][j] = __builtin_amdgcn_mfma_f32_16x16x32_bf16(af[i], bfr[j], acc[i][j], 0, 0, 0);
        }
    }
    // epilogue: row = m0+wr*64+i*16+quad*4+r, col = n0+wc*64+j*16+ln
#pragma unroll
    for (int i = 0; i < 4; i++) {
        int row_base = m0 + wr * 64 + i * 16 + quad * 4;
#pragma unroll
        for (int j = 0; j < 4; j++) {
            int col = n0 + wc * 64 + j * 16 + ln;
            float bb = (EPI == 3) ? 0.f : bias[col];
#pragma unroll
            for (int r = 0; r < 4; r++) {
                int row = row_base + r;
                size_t o = (size_t)row * N + col;
                float v = acc[i][j][r] + bb;
                if (EPI == 0) Cb[o] = f2bf(v);
                else if (EPI == 1) Cb[o] = f2bf(v > 0.f ? v : 0.f);
                else if (EPI == 2) Cf[o] = v + res[o];
                else Cf[o] = v;
            }
        }
    }
}

// ----------------------------------------------------- sparse attention ----
__global__ __launch_bounds__(256) void attn_kernel(const u16* __restrict__ QKV,
                                                   const int* __restrict__ nbr,
                                                   u16* __restrict__ outA) {
    int tid = threadIdx.x;
    int wv = blockIdx.x * 4 + (tid >> 6);  // b*1024+n
    int l = tid & 63;
    int h = l >> 4, sx = l & 15;
    int bbase = (wv >> 10) << 10;

    int nv = 0;
    if (l < 20) nv = nbr[(size_t)wv * 20 + l];

    const uint32_t* qp = (const uint32_t*)(QKV + (size_t)wv * 3072 + h * 256 + sx * 16);
    uint32_t qw[8];
    *(uint4*)(qw) = *(const uint4*)qp;
    *(uint4*)(qw + 4) = *(const uint4*)(qp + 4);
    float qf[16];
#pragma unroll
    for (int i = 0; i < 8; i++) { qf[2 * i] = bfbits_lo(qw[i]); qf[2 * i + 1] = bfbits_hi(qw[i]); }

    float wj[20];
#pragma unroll
    for (int j = 0; j < 20; j++) {
        int m = __shfl(nv, j);
        const uint32_t* kp = (const uint32_t*)(QKV + (size_t)(bbase + m) * 3072 + 1024 + h * 256 + sx * 16);
        uint32_t kw[8];
        *(uint4*)(kw) = *(const uint4*)kp;
        *(uint4*)(kw + 4) = *(const uint4*)(kp + 4);
        float acc = 0.f;
#pragma unroll
        for (int i = 0; i < 8; i++) {
            acc += qf[2 * i] * bfbits_lo(kw[i]);
            acc += qf[2 * i + 1] * bfbits_hi(kw[i]);
        }
#pragma unroll
        for (int off = 1; off < 16; off <<= 1) acc += __shfl_xor(acc, off);
        wj[j] = acc * 0.0625f;
    }
    float mx = wj[0];
#pragma unroll
    for (int j = 1; j < 20; j++) mx = fmaxf(mx, wj[j]);
    float ssum = 0.f;
#pragma unroll
    for (int j = 0; j < 20; j++) { wj[j] = __expf(wj[j] - mx); ssum += wj[j]; }
    float inv = 1.f / ssum;

    float o[16];
#pragma unroll
    for (int i = 0; i < 16; i++) o[i] = 0.f;
#pragma unroll
    for (int j = 0; j < 20; j++) {
        int m = __shfl(nv, j);
        const uint32_t* vp = (const uint32_t*)(QKV + (size_t)(bbase + m) * 3072 + 2048 + h * 256 + sx * 16);
        uint32_t vw[8];
        *(uint4*)(vw) = *(const uint4*)vp;
        *(uint4*)(vw + 4) = *(const uint4*)(vp + 4);
        float ww = wj[j] * inv;
#pragma unroll
        for (int i = 0; i < 8; i++) {
            o[2 * i] += ww * bfbits_lo(vw[i]);
            o[2 * i + 1] += ww * bfbits_hi(vw[i]);
        }
    }
    uint32_t ow[8];
#pragma unroll
    for (int i = 0; i < 8; i++) ow[i] = f2bf(o[2 * i]) | ((uint32_t)f2bf(o[2 * i + 1]) << 16);
    u16* op = outA + (size_t)wv * 1024 + h * 256 + sx * 16;
    *(uint4*)op = *(uint4*)ow;
    *((uint4*)op + 1) = *(uint4*)(ow + 4);
}

// ------------------------------------------------------------ LayerNorm ----
// ln_kernel: X -> LN (WB also writes bf16 copy)
template <int WB>
__global__ __launch_bounds__(256) void ln_kernel(const float* __restrict__ X,
                                                 const float* __restrict__ g,
                                                 const float* __restrict__ bparm,
                                                 float* __restrict__ Yf,
                                                 u16* __restrict__ Yb) {
    int tid = threadIdx.x;
    int row = blockIdx.x * 4 + (tid >> 6);
    int l = tid & 63;
    const float4* xr = (const float4*)(X + (size_t)row * 512) + l * 2;
    float4 a = xr[0], c = xr[1];
    float xs[8] = {a.x, a.y, a.z, a.w, c.x, c.y, c.z, c.w};
    float s = 0.f;
#pragma unroll
    for (int i = 0; i < 8; i++) s += xs[i];
#pragma unroll
    for (int off = 32; off >= 1; off >>= 1) s += __shfl_xor(s, off);
    float mu = s * (1.f / 512.f);
    float q = 0.f;
#pragma unroll
    for (int i = 0; i < 8; i++) { float dd = xs[i] - mu; q += dd * dd; }
#pragma unroll
    for (int off = 32; off >= 1; off >>= 1) q += __shfl_xor(q, off);
    float var = q * (1.f / 512.f);
    float rs = rsqrtf(var + 1e-5f);
    const float4* gp = (const float4*)g + l * 2;
    const float4* bp = (const float4*)bparm + l * 2;
    float4 g0 = gp[0], g1 = gp[1], b0 = bp[0], b1 = bp[1];
    float gg[8] = {g0.x, g0.y, g0.z, g0.w, g1.x, g1.y, g1.z, g1.w};
    float bbv[8] = {b0.x, b0.y, b0.z, b0.w, b1.x, b1.y, b1.z, b1.w};
    float y[8];
#pragma unroll
    for (int i = 0; i < 8; i++) y[i] = (xs[i] - mu) * rs * gg[i] + bbv[i];
    float4* yo = (float4*)(Yf + (size_t)row * 512) + l * 2;
    yo[0] = make_float4(y[0], y[1], y[2], y[3]);
    yo[1] = make_float4(y[4], y[5], y[6], y[7]);
    if (WB) {
        uint32_t w0 = f2bf(y[0]) | ((uint32_t)f2bf(y[1]) << 16);
        uint32_t w1 = f2bf(y[2]) | ((uint32_t)f2bf(y[3]) << 16);
        uint32_t w2 = f2bf(y[4]) | ((uint32_t)f2bf(y[5]) << 16);
        uint32_t w3 = f2bf(y[6]) | ((uint32_t)f2bf(y[7]) << 16);
        *(uint4*)(Yb + (size_t)row * 512 + l * 8) = make_uint4(w0, w1, w2, w3);
    }
}

// ln2p_kernel: LN over (P0 + P1 + res + biasvec) -> Yf  (split-K combine fused)
__global__ __launch_bounds__(256) void ln2p_kernel(const float* __restrict__ P0,
                                                   const float* __restrict__ P1,
                                                   const float* __restrict__ res,
                                                   const float* __restrict__ biasv,
                                                   const float* __restrict__ g,
                                                   const float* __restrict__ bparm,
                                                   float* __restrict__ Yf) {
    int tid = threadIdx.x;
    int row = blockIdx.x * 4 + (tid >> 6);
    int l = tid & 63;
    size_t base = (size_t)row * 512;
    const float4* p0 = (const float4*)(P0 + base) + l * 2;
    const float4* p1 = (const float4*)(P1 + base) + l * 2;
    const float4* rr = (const float4*)(res + base) + l * 2;
    const float4* bv = (const float4*)biasv + l * 2;
    float xs[8];
#pragma unroll
    for (int h = 0; h < 2; h++) {
        float4 a = p0[h], b = p1[h], c = rr[h], d = bv[h];
        xs[4 * h + 0] = a.x + b.x + c.x + d.x;
        xs[4 * h + 1] = a.y + b.y + c.y + d.y;
        xs[4 * h + 2] = a.z + b.z + c.z + d.z;
        xs[4 * h + 3] = a.w + b.w + c.w + d.w;
    }
    float s = 0.f;
#pragma unroll
    for (int i = 0; i < 8; i++) s += xs[i];
#pragma unroll
    for (int off = 32; off >= 1; off >>= 1) s += __shfl_xor(s, off);
    float mu = s * (1.f / 512.f);
    float q = 0.f;
#pragma unroll
    for (int i = 0; i < 8; i++) { float dd = xs[i] - mu; q += dd * dd; }
#pragma unroll
    for (int off = 32; off >= 1; off >>= 1) q += __shfl_xor(q, off);
    float var = q * (1.f / 512.f);
    float rs = rsqrtf(var + 1e-5f);
    const float4* gp = (const float4*)g + l * 2;
    const float4* bp = (const float4*)bparm + l * 2;
    float4 g0 = gp[0], g1 = gp[1], b0 = bp[0], b1 = bp[1];
    float gg[8] = {g0.x, g0.y, g0.z, g0.w, g1.x, g1.y, g1.z, g1.w};
    float bbv[8] = {b0.x, b0.y, b0.z, b0.w, b1.x, b1.y, b1.z, b1.w};
    float4* yo = (float4*)(Yf + base) + l * 2;
    float y[8];
#pragma unroll
    for (int i = 0; i < 8; i++) y[i] = (xs[i] - mu) * rs * gg[i] + bbv[i];
    yo[0] = make_float4(y[0], y[1], y[2], y[3]);
    yo[1] = make_float4(y[4], y[5], y[6], y[7]);
}

// ------------------------------------------------------------ launcher ----
extern "C" void kernel_launch(void* const* d_in, const int* in_sizes, int n_in,
                              void* d_out, int out_size, void* d_ws, size_t ws_size,
                              hipStream_t stream) {
    const float* verts = (const float*)d_in[0];
    const float* F = (const float*)d_in[1];
    const float* Wq = (const float*)d_in[2];
    const float* bq = (const float*)d_in[3];
    const float* Wk = (const float*)d_in[4];
    const float* bk = (const float*)d_in[5];
    const float* Wv = (const float*)d_in[6];
    const float* bv = (const float*)d_in[7];
    const float* Wo = (const float*)d_in[8];
    const float* bo = (const float*)d_in[9];
    const float* ln1g = (const float*)d_in[10];
    const float* ln1b = (const float*)d_in[11];
    const float* W1 = (const float*)d_in[12];
    const float* b1 = (const float*)d_in[13];
    const float* W2 = (const float*)d_in[14];
    const float* b2 = (const float*)d_in[15];
    const float* ln2g = (const float*)d_in[16];
    const float* ln2b = (const float*)d_in[17];
    float* out = (float*)d_out;

    char* ws = (char*)d_ws;
    // arena (lifetime-overlapped), total ~177.4 MB (same as round-1 footprint):
    u16* QKV = (u16*)(ws);                         // [0, 100663296) bf16 16384x3072
    u16* Hb = (u16*)(ws);                          //   reuse [0, 67108864) after attn
    float* X32 = (float*)(ws + 67108864);          //   reuse [67108864, 100663296) after attn
    u16* ATT = (u16*)(ws + 100663296);             // [100663296, +33554432)
    u16* xb = ATT;                                 //   reuse after G2
    float* P0 = (float*)(ws + 100663296);          //   reuse after G3 (G4 partial 0)
    u16* Fb = (u16*)(ws + 134217728);              // [134217728, +33554432)
    float* P1 = (float*)(ws + 134217728);          //   reuse after G1 (G4 partial 1)
    char* wsw = ws + 167772160;
    u16* WqkvT = (u16*)(wsw);                      // 3,145,728
    u16* WoT = (u16*)(wsw + 3145728);              // 1,048,576
    u16* W1T = (u16*)(wsw + 4194304);              // 2,097,152
    u16* W2T = (u16*)(wsw + 6291456);              // 2,097,152
    float* bqkv = (float*)(wsw + 8388608);         // 16,384 (padded)
    int* nbr = (int*)(wsw + 8404992);              // 1,310,720

    knn_kernel<<<4096, 256, 0, stream>>>(verts, nbr);
    convertF<<<4096, 256, 0, stream>>>(F, Fb);
    transposeW<<<dim3(32, 16), 256, 0, stream>>>(Wq, WqkvT, 512, 1024);
    transposeW<<<dim3(32, 16), 256, 0, stream>>>(Wk, WqkvT + 1024 * 512, 512, 1024);
    transposeW<<<dim3(32, 16), 256, 0, stream>>>(Wv, WqkvT + 2048 * 512, 512, 1024);
    transposeW<<<dim3(16, 32), 256, 0, stream>>>(Wo, WoT, 1024, 512);
    transposeW<<<dim3(64, 16), 256, 0, stream>>>(W1, W1T, 512, 2048);
    transposeW<<<dim3(16, 64), 256, 0, stream>>>(W2, W2T, 2048, 512);
    concat_bias<<<12, 256, 0, stream>>>(bq, bk, bv, bqkv);

    // G1: QKV = Fb @ Wqkv + bias -> bf16 [16384, 3072]
    gemm_bt<0><<<dim3(24, 128), 256, 0, stream>>>(Fb, WqkvT, bqkv, nullptr, QKV, nullptr,
                                                  16384, 3072, 512, 512, 512);
    // sparse attention -> ATT bf16 [16384, 1024]
    attn_kernel<<<4096, 256, 0, stream>>>(QKV, nbr, ATT);
    // G2: pre1 = ATT @ Wo + bo + F -> out fp32 [16384, 512]
    gemm_bt<2><<<dim3(4, 128), 256, 0, stream>>>(ATT, WoT, bo, F, nullptr, out,
                                                 16384, 512, 1024, 1024, 1024);
    // LN1: out -> X32 fp32 + xb bf16
    ln_kernel<1><<<4096, 256, 0, stream>>>(out, ln1g, ln1b, X32, xb);
    // G3: Hb = relu(xb @ W1 + b1) -> bf16 [16384, 2048]
    gemm_bt<1><<<dim3(16, 128), 256, 0, stream>>>(xb, W1T, b1, nullptr, Hb, nullptr,
                                                  16384, 2048, 512, 512, 512);
    // G4 split-K x2: P0 = Hb[:, :1024] @ W2T[:, :1024]^T ; P1 = second half
    gemm_bt<3><<<dim3(4, 128), 256, 0, stream>>>(Hb, W2T, nullptr, nullptr, nullptr, P0,
                                                 16384, 512, 1024, 2048, 2048);
    gemm_bt<3><<<dim3(4, 128), 256, 0, stream>>>(Hb + 1024, W2T + 1024, nullptr, nullptr, nullptr, P1,
                                                 16384, 512, 1024, 2048, 2048);
    // LN2: LN(P0 + P1 + b2 + X32) -> out
    ln2p_kernel<<<4096, 256, 0, stream>>>(P0, P1, X32, b2, ln2g, ln2b, out);
}